// Round 1
// baseline (899.531 us; speedup 1.0000x reference)
//
#include <hip/hip_runtime.h>

#define N_TOK 32768
#define H 128
#define I_DIM 512
#define E 8
#define EPS 1e-5f
#define TM 32

typedef __attribute__((ext_vector_type(8))) short short8;
typedef __attribute__((ext_vector_type(4))) float f32x4;
typedef __attribute__((ext_vector_type(8))) __bf16 bf16x8;

__device__ inline unsigned short f2bf(float f){
  unsigned int u = __builtin_bit_cast(unsigned int, f);
  u += 0x7fffu + ((u >> 16) & 1u);
  return (unsigned short)(u >> 16);
}
__device__ inline float bf2f(unsigned short s){
  unsigned int u = ((unsigned int)s) << 16;
  return __builtin_bit_cast(float, u);
}
__device__ inline float gelu_exact(float x){
  return 0.5f * x * (1.f + erff(x * 0.70710678118654752f));
}
__device__ inline f32x4 mfma16(short8 a, short8 b, f32x4 c){
  return __builtin_amdgcn_mfma_f32_16x16x32_bf16(
      __builtin_bit_cast(bf16x8, a), __builtin_bit_cast(bf16x8, b), c, 0, 0, 0);
}

// ---------------- Kernel A: repack weights to bf16 MFMA-B fragment order ----
// B-frag for 16x16x32: lane l holds B[k0 + (l>>4)*8 + j][n0 + (l&15)], j=0..7.
// Packed: [e][n_tile][k_tile][lane][j]  -> wave reads 16B/lane fully coalesced.
__global__ __launch_bounds__(256) void k_prep(const float* __restrict__ w1,
                                              const float* __restrict__ w2,
                                              unsigned short* __restrict__ w1p,
                                              unsigned short* __restrict__ w2p){
  int idx = blockIdx.x * 256 + threadIdx.x;   // 0 .. 524287
  {
    // w1: [E][I][H];  GEMM1: t[m][i] = sum_h a1[m][h]*w1[i][h]; N-dim=i, K-dim=h
    float v = w1[idx];
    int e = idx >> 16, r = idx & 65535;
    int i = r >> 7, h = r & 127;
    int it = i >> 4, il = i & 15;
    int kt = h >> 5, lh = (h >> 3) & 3, j = h & 7;
    int l = lh * 16 + il;
    size_t p = ((((size_t)e * 32 + it) * 4 + kt) * 64 + l) * 8 + j;
    w1p[p] = f2bf(v);
  }
  {
    // w2: [E][H][I];  GEMM2: o[m][h] = sum_i a2[m][i]*w2[h][i]; N-dim=h, K-dim=i
    float v = w2[idx];
    int e = idx >> 16, r = idx & 65535;
    int h = r >> 9, i = r & 511;
    int ht = h >> 4, hl = h & 15;
    int kt = i >> 5, lh = (i >> 3) & 3, j = i & 7;
    int l = lh * 16 + hl;
    size_t p = ((((size_t)e * 8 + ht) * 16 + kt) * 64 + l) * 8 + j;
    w2p[p] = f2bf(v);
  }
}

// ---------------- Kernel B: gating softmax/top2 + token layernorm -----------
__global__ __launch_bounds__(256) void k_gate(const float* __restrict__ x,
                                              const float* __restrict__ gw,
                                              const float* __restrict__ gb,
                                              unsigned short* __restrict__ xn,
                                              int* __restrict__ cnt,
                                              int* __restrict__ list,
                                              float* __restrict__ score){
  __shared__ float gws[E * H];
  __shared__ float gbs[E];
  int tid = threadIdx.x;
  for (int i = tid; i < E * H; i += 256) gws[i] = gw[i];
  if (tid < E) gbs[tid] = gb[tid];
  __syncthreads();

  int wave = tid >> 6, lane = tid & 63;
  int tok = blockIdx.x * 4 + wave;
  const float* xp = x + (size_t)tok * H;
  float2 v = *(const float2*)(xp + lane * 2);

  float s = v.x + v.y;
  float sq = v.x * v.x + v.y * v.y;
  float lg[E];
  #pragma unroll
  for (int e = 0; e < E; e++)
    lg[e] = v.x * gws[e * H + lane * 2] + v.y * gws[e * H + lane * 2 + 1];

  #pragma unroll
  for (int m = 1; m < 64; m <<= 1){
    s  += __shfl_xor(s, m);
    sq += __shfl_xor(sq, m);
    #pragma unroll
    for (int e = 0; e < E; e++) lg[e] += __shfl_xor(lg[e], m);
  }

  float mu = s * (1.f / H);
  float var = sq * (1.f / H) - mu * mu;
  float rsig = rsqrtf(fmaxf(var, 0.f) + EPS);

  // store normalized x (bf16)
  unsigned short b0 = f2bf((v.x - mu) * rsig);
  unsigned short b1 = f2bf((v.y - mu) * rsig);
  unsigned int packed = ((unsigned int)b1 << 16) | b0;
  *(unsigned int*)(xn + (size_t)tok * H + lane * 2) = packed;

  // softmax over 8 + top2 (all lanes redundantly)
  float mx = -1e30f;
  #pragma unroll
  for (int e = 0; e < E; e++){ lg[e] += gbs[e]; mx = fmaxf(mx, lg[e]); }
  float p[E], sum = 0.f;
  #pragma unroll
  for (int e = 0; e < E; e++){ p[e] = __expf(lg[e] - mx); sum += p[e]; }
  float inv = 1.f / sum;
  int e0 = 0; float p0 = p[0];
  #pragma unroll
  for (int e = 1; e < E; e++) if (p[e] > p0){ e0 = e; p0 = p[e]; }
  int e1 = -1; float p1 = -1.f;
  #pragma unroll
  for (int e = 0; e < E; e++) if (e != e0 && p[e] > p1){ e1 = e; p1 = p[e]; }

  if (lane == 0){
    int pos0 = atomicAdd(&cnt[e0], 1);
    list[e0 * N_TOK + pos0] = tok;  score[e0 * N_TOK + pos0] = p0 * inv;
    int pos1 = atomicAdd(&cnt[e1], 1);
    list[e1 * N_TOK + pos1] = tok;  score[e1 * N_TOK + pos1] = p1 * inv;
  }
}

// ---------------- Kernel C: grouped expert MLP (MFMA) -----------------------
__global__ __launch_bounds__(256) void k_expert(
    const unsigned short* __restrict__ xn,
    const float* __restrict__ ln1g, const float* __restrict__ ln1b,
    const unsigned short* __restrict__ w1p,
    const float* __restrict__ ln2g, const float* __restrict__ ln2b,
    const unsigned short* __restrict__ w2p,
    const float* __restrict__ b2,
    const int* __restrict__ cnt, const int* __restrict__ list,
    const float* __restrict__ score,
    float* __restrict__ out){
  int e = blockIdx.y;
  int ne = cnt[e];
  int base = blockIdx.x * TM;
  if (base >= ne) return;
  int rows = min(TM, ne - base);

  __shared__ __align__(16) unsigned short a1[TM * H];     // 8 KB, swizzled
  __shared__ __align__(16) unsigned short a2[TM * I_DIM]; // 32 KB, swizzled
  __shared__ float g1s[H], b1s[H];
  __shared__ float psum[2][TM][4];
  __shared__ int   toks[TM];
  __shared__ float scs[TM];

  int tid = threadIdx.x, wave = tid >> 6, lane = tid & 63;
  const int l15 = lane & 15, l4 = lane >> 4;

  if (tid < H){ g1s[tid] = ln1g[e * H + tid]; b1s[tid] = ln1b[e * H + tid]; }
  if (tid < TM){
    int gpos = base + tid;
    if (gpos < ne){ toks[tid] = list[e * N_TOK + gpos]; scs[tid] = score[e * N_TOK + gpos]; }
    else          { toks[tid] = -1;                     scs[tid] = 0.f; }
  }
  __syncthreads();

  // ---- stage a1 = gelu(xn * g1 + b1), bf16, XOR-swizzled -------------------
  {
    int r = tid >> 3, c0 = (tid & 7) * 16;
    int t_ = toks[r];
    short8 o0, o1;
    if (t_ >= 0){
      const unsigned short* xr = xn + (size_t)t_ * H + c0;
      short8 v0 = *(const short8*)xr;
      short8 v1 = *(const short8*)(xr + 8);
      #pragma unroll
      for (int j = 0; j < 8; j++){
        int c = c0 + j;
        float f = bf2f((unsigned short)v0[j]);
        o0[j] = (short)f2bf(gelu_exact(f * g1s[c] + b1s[c]));
      }
      #pragma unroll
      for (int j = 0; j < 8; j++){
        int c = c0 + 8 + j;
        float f = bf2f((unsigned short)v1[j]);
        o1[j] = (short)f2bf(gelu_exact(f * g1s[c] + b1s[c]));
      }
    } else {
      #pragma unroll
      for (int j = 0; j < 8; j++){ o0[j] = 0; o1[j] = 0; }
    }
    int byt = r * 256 + c0 * 2;
    int swz = (r & 7) << 4;
    *(short8*)((char*)a1 + (byt ^ swz)) = o0;
    *(short8*)((char*)a1 + ((byt + 16) ^ swz)) = o1;
  }

  // preload ln2 affine for this lane's columns
  float g2r[8], b2r[8];
  #pragma unroll
  for (int it = 0; it < 8; it++){
    int c = wave * 128 + it * 16 + l15;
    g2r[it] = ln2g[e * I_DIM + c];
    b2r[it] = ln2b[e * I_DIM + c];
  }
  __syncthreads();

  // ---- GEMM1: t[32 x 512] ; wave owns i-cols [wave*128, wave*128+128) ------
  f32x4 acc[2][8];
  #pragma unroll
  for (int mt = 0; mt < 2; mt++)
    #pragma unroll
    for (int it = 0; it < 8; it++){ f32x4 z = {0.f,0.f,0.f,0.f}; acc[mt][it] = z; }

  #pragma unroll
  for (int kt = 0; kt < 4; ++kt){
    short8 af[2];
    #pragma unroll
    for (int mt = 0; mt < 2; mt++){
      int r = mt * 16 + l15;
      int byt = r * 256 + (kt * 32 + l4 * 8) * 2;
      af[mt] = *(const short8*)((const char*)a1 + (byt ^ ((r & 7) << 4)));
    }
    #pragma unroll
    for (int it = 0; it < 8; ++it){
      const short8 bf = *(const short8*)(w1p +
          ((((size_t)e * 32 + wave * 8 + it) * 4 + kt) * 64 + lane) * 8);
      acc[0][it] = mfma16(af[0], bf, acc[0][it]);
      acc[1][it] = mfma16(af[1], bf, acc[1][it]);
    }
  }

  // ---- LN2 partial sums (in-register), cross-wave combine via LDS ----------
  float ps[2][4], pq[2][4];
  #pragma unroll
  for (int mt = 0; mt < 2; mt++)
    #pragma unroll
    for (int r = 0; r < 4; r++){
      float s_ = 0.f, q_ = 0.f;
      #pragma unroll
      for (int it = 0; it < 8; it++){ float v = acc[mt][it][r]; s_ += v; q_ += v * v; }
      ps[mt][r] = s_; pq[mt][r] = q_;
    }
  #pragma unroll
  for (int m = 1; m < 16; m <<= 1){
    #pragma unroll
    for (int mt = 0; mt < 2; mt++)
      #pragma unroll
      for (int r = 0; r < 4; r++){
        ps[mt][r] += __shfl_xor(ps[mt][r], m);
        pq[mt][r] += __shfl_xor(pq[mt][r], m);
      }
  }
  if (l15 == 0){
    #pragma unroll
    for (int mt = 0; mt < 2; mt++)
      #pragma unroll
      for (int r = 0; r < 4; r++){
        int row = mt * 16 + l4 * 4 + r;
        psum[0][row][wave] = ps[mt][r];
        psum[1][row][wave] = pq[mt][r];
      }
  }
  __syncthreads();

  // ---- LN2 + gelu -> a2 (bf16, swizzled) -----------------------------------
  #pragma unroll
  for (int mt = 0; mt < 2; mt++){
    #pragma unroll
    for (int r = 0; r < 4; r++){
      int row = mt * 16 + l4 * 4 + r;
      float S = psum[0][row][0] + psum[0][row][1] + psum[0][row][2] + psum[0][row][3];
      float Q = psum[1][row][0] + psum[1][row][1] + psum[1][row][2] + psum[1][row][3];
      float mu = S * (1.f / I_DIM);
      float var = Q * (1.f / I_DIM) - mu * mu;
      float rsig = rsqrtf(fmaxf(var, 0.f) + EPS);
      #pragma unroll
      for (int it = 0; it < 8; it++){
        int col = wave * 128 + it * 16 + l15;
        float h2 = (acc[mt][it][r] - mu) * rsig * g2r[it] + b2r[it];
        unsigned short ob = f2bf(gelu_exact(h2));
        int byt = row * 1024 + col * 2;
        *((unsigned short*)((char*)a2 + (byt ^ ((row & 7) << 4)))) = ob;
      }
    }
  }
  __syncthreads();

  // ---- GEMM2: o[32 x 128] ; wave owns h-cols [wave*32, wave*32+32) ---------
  f32x4 c2[2][2];
  #pragma unroll
  for (int mt = 0; mt < 2; mt++)
    #pragma unroll
    for (int ht = 0; ht < 2; ht++){ f32x4 z = {0.f,0.f,0.f,0.f}; c2[mt][ht] = z; }

  #pragma unroll
  for (int kt = 0; kt < 16; ++kt){
    short8 af[2];
    #pragma unroll
    for (int mt = 0; mt < 2; mt++){
      int r = mt * 16 + l15;
      int byt = r * 1024 + (kt * 32 + l4 * 8) * 2;
      af[mt] = *(const short8*)((const char*)a2 + (byt ^ ((r & 7) << 4)));
    }
    #pragma unroll
    for (int ht = 0; ht < 2; ++ht){
      const short8 bf = *(const short8*)(w2p +
          ((((size_t)e * 8 + wave * 2 + ht) * 16 + kt) * 64 + lane) * 8);
      c2[0][ht] = mfma16(af[0], bf, c2[0][ht]);
      c2[1][ht] = mfma16(af[1], bf, c2[1][ht]);
    }
  }

  // ---- epilogue: + b2, * score, atomicAdd into out -------------------------
  float bb[2];
  #pragma unroll
  for (int ht = 0; ht < 2; ht++) bb[ht] = b2[e * H + wave * 32 + ht * 16 + l15];
  #pragma unroll
  for (int mt = 0; mt < 2; mt++){
    #pragma unroll
    for (int ht = 0; ht < 2; ht++){
      #pragma unroll
      for (int r = 0; r < 4; r++){
        int row = mt * 16 + l4 * 4 + r;
        if (row < rows){
          int t_ = toks[row]; float sc = scs[row];
          int col = wave * 32 + ht * 16 + l15;
          atomicAdd(out + (size_t)t_ * H + col, (c2[mt][ht][r] + bb[ht]) * sc);
        }
      }
    }
  }
}

extern "C" void kernel_launch(void* const* d_in, const int* in_sizes, int n_in,
                              void* d_out, int out_size, void* d_ws, size_t ws_size,
                              hipStream_t stream){
  const float* x     = (const float*)d_in[0];
  const float* gw    = (const float*)d_in[1];
  const float* gb    = (const float*)d_in[2];
  const float* ln1g  = (const float*)d_in[3];
  const float* ln1b  = (const float*)d_in[4];
  const float* w1    = (const float*)d_in[5];
  const float* ln2g  = (const float*)d_in[6];
  const float* ln2b  = (const float*)d_in[7];
  const float* w2    = (const float*)d_in[8];
  const float* b2    = (const float*)d_in[9];
  float* out = (float*)d_out;

  char* w = (char*)d_ws;
  unsigned short* xn  = (unsigned short*)w;            w += (size_t)N_TOK * H * 2;   // 8 MB
  unsigned short* w1p = (unsigned short*)w;            w += (size_t)E * I_DIM * H * 2; // 1 MB
  unsigned short* w2p = (unsigned short*)w;            w += (size_t)E * H * I_DIM * 2; // 1 MB
  int*   list  = (int*)w;                              w += (size_t)E * N_TOK * 4;   // 1 MB
  float* score = (float*)w;                            w += (size_t)E * N_TOK * 4;   // 1 MB
  int*   cnt   = (int*)w;                              w += 256;

  hipMemsetAsync(cnt, 0, 256, stream);
  hipMemsetAsync(out, 0, (size_t)out_size * sizeof(float), stream);

  k_prep<<<dim3((E * I_DIM * H) / 256), dim3(256), 0, stream>>>(w1, w2, w1p, w2p);
  k_gate<<<dim3(N_TOK / 4), dim3(256), 0, stream>>>(x, gw, gb, xn, cnt, list, score);
  k_expert<<<dim3(N_TOK / TM, E), dim3(256), 0, stream>>>(
      xn, ln1g, ln1b, w1p, ln2g, ln2b, w2p, b2, cnt, list, score, out);
}

// Round 2
// 192.671 us; speedup vs baseline: 4.6687x; 4.6687x over previous
//
#include <hip/hip_runtime.h>

#define N_TOK 32768
#define H 128
#define I_DIM 512
#define E 8
#define EPS 1e-5f
#define TM 32
#define GATE_TPB 128   // tokens per block in k_gate

typedef __attribute__((ext_vector_type(8))) short short8;
typedef __attribute__((ext_vector_type(4))) float f32x4;
typedef __attribute__((ext_vector_type(8))) __bf16 bf16x8;

__device__ inline unsigned short f2bf(float f){
  unsigned int u = __builtin_bit_cast(unsigned int, f);
  u += 0x7fffu + ((u >> 16) & 1u);
  return (unsigned short)(u >> 16);
}
__device__ inline float bf2f(unsigned short s){
  unsigned int u = ((unsigned int)s) << 16;
  return __builtin_bit_cast(float, u);
}
__device__ inline float gelu_exact(float x){
  return 0.5f * x * (1.f + erff(x * 0.70710678118654752f));
}
__device__ inline f32x4 mfma16(short8 a, short8 b, f32x4 c){
  return __builtin_amdgcn_mfma_f32_16x16x32_bf16(
      __builtin_bit_cast(bf16x8, a), __builtin_bit_cast(bf16x8, b), c, 0, 0, 0);
}

// ---------------- Kernel A: repack weights to bf16 MFMA-B fragment order ----
// B-frag for 16x16x32: lane l holds B[k0 + (l>>4)*8 + j][n0 + (l&15)], j=0..7.
// Packed: [e][n_tile][k_tile][lane][j]  -> wave reads 16B/lane fully coalesced.
__global__ __launch_bounds__(256) void k_prep(const float* __restrict__ w1,
                                              const float* __restrict__ w2,
                                              unsigned short* __restrict__ w1p,
                                              unsigned short* __restrict__ w2p){
  int idx = blockIdx.x * 256 + threadIdx.x;   // 0 .. 524287
  {
    // w1: [E][I][H];  GEMM1: t[m][i] = sum_h a1[m][h]*w1[i][h]; N-dim=i, K-dim=h
    float v = w1[idx];
    int e = idx >> 16, r = idx & 65535;
    int i = r >> 7, h = r & 127;
    int it = i >> 4, il = i & 15;
    int kt = h >> 5, lh = (h >> 3) & 3, j = h & 7;
    int l = lh * 16 + il;
    size_t p = ((((size_t)e * 32 + it) * 4 + kt) * 64 + l) * 8 + j;
    w1p[p] = f2bf(v);
  }
  {
    // w2: [E][H][I];  GEMM2: o[m][h] = sum_i a2[m][i]*w2[h][i]; N-dim=h, K-dim=i
    float v = w2[idx];
    int e = idx >> 16, r = idx & 65535;
    int h = r >> 9, i = r & 511;
    int ht = h >> 4, hl = h & 15;
    int kt = i >> 5, lh = (i >> 3) & 3, j = i & 7;
    int l = lh * 16 + hl;
    size_t p = ((((size_t)e * 8 + ht) * 16 + kt) * 64 + l) * 8 + j;
    w2p[p] = f2bf(v);
  }
}

// ---------------- Kernel B: gating softmax/top2 + token layernorm -----------
// 128 tokens / block, 4 waves (wave-per-token x 32 iter). Hierarchical atomics:
// LDS per-expert counters -> ONE global atomicAdd per (block, expert) to
// reserve a range -> plain stores of list/score. Cuts same-address global
// atomics 65536 -> 2048 (was 750 us of serialized L2 atomics).
__global__ __launch_bounds__(256) void k_gate(const float* __restrict__ x,
                                              const float* __restrict__ gw,
                                              const float* __restrict__ gb,
                                              unsigned short* __restrict__ xn,
                                              int* __restrict__ cnt,
                                              int* __restrict__ list,
                                              float* __restrict__ score){
  __shared__ float gws[E * H];
  __shared__ float gbs[E];
  __shared__ int   lcnt[E];
  __shared__ int   gbase[E];
  __shared__ int   te[2][GATE_TPB];
  __shared__ float tsc[2][GATE_TPB];
  __shared__ int   tlp[2][GATE_TPB];

  int tid = threadIdx.x;
  for (int i = tid; i < E * H; i += 256) gws[i] = gw[i];
  if (tid < E){ gbs[tid] = gb[tid]; lcnt[tid] = 0; }
  __syncthreads();

  int wave = tid >> 6, lane = tid & 63;
  int tok0 = blockIdx.x * GATE_TPB;

  for (int t = 0; t < GATE_TPB / 4; ++t){
    int lt = wave * (GATE_TPB / 4) + t;
    int tok = tok0 + lt;
    const float* xp = x + (size_t)tok * H;
    float2 v = *(const float2*)(xp + lane * 2);

    float s = v.x + v.y;
    float sq = v.x * v.x + v.y * v.y;
    float lg[E];
    #pragma unroll
    for (int e = 0; e < E; e++)
      lg[e] = v.x * gws[e * H + lane * 2] + v.y * gws[e * H + lane * 2 + 1];

    #pragma unroll
    for (int m = 1; m < 64; m <<= 1){
      s  += __shfl_xor(s, m);
      sq += __shfl_xor(sq, m);
      #pragma unroll
      for (int e = 0; e < E; e++) lg[e] += __shfl_xor(lg[e], m);
    }

    float mu = s * (1.f / H);
    float var = sq * (1.f / H) - mu * mu;
    float rsig = rsqrtf(fmaxf(var, 0.f) + EPS);

    unsigned short b0 = f2bf((v.x - mu) * rsig);
    unsigned short b1 = f2bf((v.y - mu) * rsig);
    unsigned int packed = ((unsigned int)b1 << 16) | b0;
    *(unsigned int*)(xn + (size_t)tok * H + lane * 2) = packed;

    if (lane == 0){
      float mx = -1e30f;
      #pragma unroll
      for (int e = 0; e < E; e++){ lg[e] += gbs[e]; mx = fmaxf(mx, lg[e]); }
      float p[E], sum = 0.f;
      #pragma unroll
      for (int e = 0; e < E; e++){ p[e] = __expf(lg[e] - mx); sum += p[e]; }
      float inv = 1.f / sum;
      int e0 = 0; float p0 = p[0];
      #pragma unroll
      for (int e = 1; e < E; e++) if (p[e] > p0){ e0 = e; p0 = p[e]; }
      int e1 = -1; float p1 = -1.f;
      #pragma unroll
      for (int e = 0; e < E; e++) if (e != e0 && p[e] > p1){ e1 = e; p1 = p[e]; }
      te[0][lt] = e0; tsc[0][lt] = p0 * inv; tlp[0][lt] = atomicAdd(&lcnt[e0], 1);
      te[1][lt] = e1; tsc[1][lt] = p1 * inv; tlp[1][lt] = atomicAdd(&lcnt[e1], 1);
    }
  }
  __syncthreads();
  if (tid < E) gbase[tid] = atomicAdd(&cnt[tid], lcnt[tid]);
  __syncthreads();
  if (tid < GATE_TPB){
    int tok = tok0 + tid;
    #pragma unroll
    for (int k2 = 0; k2 < 2; k2++){
      int ee = te[k2][tid];
      int pos = gbase[ee] + tlp[k2][tid];
      list[ee * N_TOK + pos] = tok;
      score[ee * N_TOK + pos] = tsc[k2][tid];
    }
  }
}

// ---------------- Kernel C: grouped expert MLP (MFMA) -----------------------
__global__ __launch_bounds__(256) void k_expert(
    const unsigned short* __restrict__ xn,
    const float* __restrict__ ln1g, const float* __restrict__ ln1b,
    const unsigned short* __restrict__ w1p,
    const float* __restrict__ ln2g, const float* __restrict__ ln2b,
    const unsigned short* __restrict__ w2p,
    const float* __restrict__ b2,
    const int* __restrict__ cnt, const int* __restrict__ list,
    const float* __restrict__ score,
    float* __restrict__ out){
  int e = blockIdx.y;
  int ne = cnt[e];
  int base = blockIdx.x * TM;
  if (base >= ne) return;
  int rows = min(TM, ne - base);

  __shared__ __align__(16) unsigned short a1[TM * H];     // 8 KB, swizzled
  __shared__ __align__(16) unsigned short a2[TM * I_DIM]; // 32 KB, swizzled
  __shared__ float g1s[H], b1s[H];
  __shared__ float psum[2][TM][4];
  __shared__ int   toks[TM];
  __shared__ float scs[TM];

  int tid = threadIdx.x, wave = tid >> 6, lane = tid & 63;
  const int l15 = lane & 15, l4 = lane >> 4;

  if (tid < H){ g1s[tid] = ln1g[e * H + tid]; b1s[tid] = ln1b[e * H + tid]; }
  if (tid < TM){
    int gpos = base + tid;
    if (gpos < ne){ toks[tid] = list[e * N_TOK + gpos]; scs[tid] = score[e * N_TOK + gpos]; }
    else          { toks[tid] = -1;                     scs[tid] = 0.f; }
  }
  __syncthreads();

  // ---- stage a1 = gelu(xn * g1 + b1), bf16, XOR-swizzled -------------------
  {
    int r = tid >> 3, c0 = (tid & 7) * 16;
    int t_ = toks[r];
    short8 o0, o1;
    if (t_ >= 0){
      const unsigned short* xr = xn + (size_t)t_ * H + c0;
      short8 v0 = *(const short8*)xr;
      short8 v1 = *(const short8*)(xr + 8);
      #pragma unroll
      for (int j = 0; j < 8; j++){
        int c = c0 + j;
        float f = bf2f((unsigned short)v0[j]);
        o0[j] = (short)f2bf(gelu_exact(f * g1s[c] + b1s[c]));
      }
      #pragma unroll
      for (int j = 0; j < 8; j++){
        int c = c0 + 8 + j;
        float f = bf2f((unsigned short)v1[j]);
        o1[j] = (short)f2bf(gelu_exact(f * g1s[c] + b1s[c]));
      }
    } else {
      #pragma unroll
      for (int j = 0; j < 8; j++){ o0[j] = 0; o1[j] = 0; }
    }
    int byt = r * 256 + c0 * 2;
    int swz = (r & 7) << 4;
    *(short8*)((char*)a1 + (byt ^ swz)) = o0;
    *(short8*)((char*)a1 + ((byt + 16) ^ swz)) = o1;
  }

  // preload ln2 affine for this lane's columns
  float g2r[8], b2r[8];
  #pragma unroll
  for (int it = 0; it < 8; it++){
    int c = wave * 128 + it * 16 + l15;
    g2r[it] = ln2g[e * I_DIM + c];
    b2r[it] = ln2b[e * I_DIM + c];
  }
  __syncthreads();

  // ---- GEMM1: t[32 x 512] ; wave owns i-cols [wave*128, wave*128+128) ------
  f32x4 acc[2][8];
  #pragma unroll
  for (int mt = 0; mt < 2; mt++)
    #pragma unroll
    for (int it = 0; it < 8; it++){ f32x4 z = {0.f,0.f,0.f,0.f}; acc[mt][it] = z; }

  #pragma unroll
  for (int kt = 0; kt < 4; ++kt){
    short8 af[2];
    #pragma unroll
    for (int mt = 0; mt < 2; mt++){
      int r = mt * 16 + l15;
      int byt = r * 256 + (kt * 32 + l4 * 8) * 2;
      af[mt] = *(const short8*)((const char*)a1 + (byt ^ ((r & 7) << 4)));
    }
    #pragma unroll
    for (int it = 0; it < 8; ++it){
      const short8 bf = *(const short8*)(w1p +
          ((((size_t)e * 32 + wave * 8 + it) * 4 + kt) * 64 + lane) * 8);
      acc[0][it] = mfma16(af[0], bf, acc[0][it]);
      acc[1][it] = mfma16(af[1], bf, acc[1][it]);
    }
  }

  // ---- LN2 partial sums (in-register), cross-wave combine via LDS ----------
  float ps[2][4], pq[2][4];
  #pragma unroll
  for (int mt = 0; mt < 2; mt++)
    #pragma unroll
    for (int r = 0; r < 4; r++){
      float s_ = 0.f, q_ = 0.f;
      #pragma unroll
      for (int it = 0; it < 8; it++){ float v = acc[mt][it][r]; s_ += v; q_ += v * v; }
      ps[mt][r] = s_; pq[mt][r] = q_;
    }
  #pragma unroll
  for (int m = 1; m < 16; m <<= 1){
    #pragma unroll
    for (int mt = 0; mt < 2; mt++)
      #pragma unroll
      for (int r = 0; r < 4; r++){
        ps[mt][r] += __shfl_xor(ps[mt][r], m);
        pq[mt][r] += __shfl_xor(pq[mt][r], m);
      }
  }
  if (l15 == 0){
    #pragma unroll
    for (int mt = 0; mt < 2; mt++)
      #pragma unroll
      for (int r = 0; r < 4; r++){
        int row = mt * 16 + l4 * 4 + r;
        psum[0][row][wave] = ps[mt][r];
        psum[1][row][wave] = pq[mt][r];
      }
  }
  __syncthreads();

  // ---- LN2 + gelu -> a2 (bf16, swizzled) -----------------------------------
  #pragma unroll
  for (int mt = 0; mt < 2; mt++){
    #pragma unroll
    for (int r = 0; r < 4; r++){
      int row = mt * 16 + l4 * 4 + r;
      float S = psum[0][row][0] + psum[0][row][1] + psum[0][row][2] + psum[0][row][3];
      float Q = psum[1][row][0] + psum[1][row][1] + psum[1][row][2] + psum[1][row][3];
      float mu = S * (1.f / I_DIM);
      float var = Q * (1.f / I_DIM) - mu * mu;
      float rsig = rsqrtf(fmaxf(var, 0.f) + EPS);
      #pragma unroll
      for (int it = 0; it < 8; it++){
        int col = wave * 128 + it * 16 + l15;
        float h2 = (acc[mt][it][r] - mu) * rsig * g2r[it] + b2r[it];
        unsigned short ob = f2bf(gelu_exact(h2));
        int byt = row * 1024 + col * 2;
        *((unsigned short*)((char*)a2 + (byt ^ ((row & 7) << 4)))) = ob;
      }
    }
  }
  __syncthreads();

  // ---- GEMM2: o[32 x 128] ; wave owns h-cols [wave*32, wave*32+32) ---------
  f32x4 c2[2][2];
  #pragma unroll
  for (int mt = 0; mt < 2; mt++)
    #pragma unroll
    for (int ht = 0; ht < 2; ht++){ f32x4 z = {0.f,0.f,0.f,0.f}; c2[mt][ht] = z; }

  #pragma unroll
  for (int kt = 0; kt < 16; ++kt){
    short8 af[2];
    #pragma unroll
    for (int mt = 0; mt < 2; mt++){
      int r = mt * 16 + l15;
      int byt = r * 1024 + (kt * 32 + l4 * 8) * 2;
      af[mt] = *(const short8*)((const char*)a2 + (byt ^ ((r & 7) << 4)));
    }
    #pragma unroll
    for (int ht = 0; ht < 2; ++ht){
      const short8 bf = *(const short8*)(w2p +
          ((((size_t)e * 8 + wave * 2 + ht) * 16 + kt) * 64 + lane) * 8);
      c2[0][ht] = mfma16(af[0], bf, c2[0][ht]);
      c2[1][ht] = mfma16(af[1], bf, c2[1][ht]);
    }
  }

  // ---- epilogue: + b2, * score, atomicAdd into out -------------------------
  float bb[2];
  #pragma unroll
  for (int ht = 0; ht < 2; ht++) bb[ht] = b2[e * H + wave * 32 + ht * 16 + l15];
  #pragma unroll
  for (int mt = 0; mt < 2; mt++){
    #pragma unroll
    for (int ht = 0; ht < 2; ht++){
      #pragma unroll
      for (int r = 0; r < 4; r++){
        int row = mt * 16 + l4 * 4 + r;
        if (row < rows){
          int t_ = toks[row]; float sc = scs[row];
          int col = wave * 32 + ht * 16 + l15;
          atomicAdd(out + (size_t)t_ * H + col, (c2[mt][ht][r] + bb[ht]) * sc);
        }
      }
    }
  }
}

extern "C" void kernel_launch(void* const* d_in, const int* in_sizes, int n_in,
                              void* d_out, int out_size, void* d_ws, size_t ws_size,
                              hipStream_t stream){
  const float* x     = (const float*)d_in[0];
  const float* gw    = (const float*)d_in[1];
  const float* gb    = (const float*)d_in[2];
  const float* ln1g  = (const float*)d_in[3];
  const float* ln1b  = (const float*)d_in[4];
  const float* w1    = (const float*)d_in[5];
  const float* ln2g  = (const float*)d_in[6];
  const float* ln2b  = (const float*)d_in[7];
  const float* w2    = (const float*)d_in[8];
  const float* b2    = (const float*)d_in[9];
  float* out = (float*)d_out;

  char* w = (char*)d_ws;
  unsigned short* xn  = (unsigned short*)w;            w += (size_t)N_TOK * H * 2;   // 8 MB
  unsigned short* w1p = (unsigned short*)w;            w += (size_t)E * I_DIM * H * 2; // 1 MB
  unsigned short* w2p = (unsigned short*)w;            w += (size_t)E * H * I_DIM * 2; // 1 MB
  int*   list  = (int*)w;                              w += (size_t)E * N_TOK * 4;   // 1 MB
  float* score = (float*)w;                            w += (size_t)E * N_TOK * 4;   // 1 MB
  int*   cnt   = (int*)w;                              w += 256;

  hipMemsetAsync(cnt, 0, 256, stream);
  hipMemsetAsync(out, 0, (size_t)out_size * sizeof(float), stream);

  k_prep<<<dim3((E * I_DIM * H) / 256), dim3(256), 0, stream>>>(w1, w2, w1p, w2p);
  k_gate<<<dim3(N_TOK / GATE_TPB), dim3(256), 0, stream>>>(x, gw, gb, xn, cnt, list, score);
  k_expert<<<dim3(N_TOK / TM, E), dim3(256), 0, stream>>>(
      xn, ln1g, ln1b, w1p, ln2g, ln2b, w2p, b2, cnt, list, score, out);
}

// Round 3
// 166.080 us; speedup vs baseline: 5.4162x; 1.1601x over previous
//
#include <hip/hip_runtime.h>

#define N_TOK 32768
#define H 128
#define I_DIM 512
#define E 8
#define EPS 1e-5f
#define TM 32
#define GATE_TPB 128   // tokens per block in k_gate

typedef __attribute__((ext_vector_type(8))) short short8;
typedef __attribute__((ext_vector_type(4))) float f32x4;
typedef __attribute__((ext_vector_type(2))) unsigned int u32x2;
typedef __attribute__((ext_vector_type(8))) __bf16 bf16x8;

__device__ inline unsigned short f2bf(float f){
  unsigned int u = __builtin_bit_cast(unsigned int, f);
  u += 0x7fffu + ((u >> 16) & 1u);
  return (unsigned short)(u >> 16);
}
__device__ inline float bf2f(unsigned short s){
  unsigned int u = ((unsigned int)s) << 16;
  return __builtin_bit_cast(float, u);
}
// fast GELU (tanh form), |err| <= ~3e-4 vs exact erf-GELU:
// gelu(x) = x * sigmoid(2*0.7978845608*(x + 0.044715 x^3))
//         = x * (1 - rcp(1 + exp2(x*(B + A*x^2)))),  B=2*log2e*c, A=B*0.044715
__device__ inline float gelu_fast(float x){
  const float A = 0.10294517f;     // 2*log2(e)*0.7978845608*0.044715
  const float B = 2.30214175f;     // 2*log2(e)*0.7978845608
  float x2 = x * x;
  float v  = __builtin_fmaf(x2, A, B);
  float z  = __builtin_amdgcn_exp2f(v * x);
  float r  = __builtin_amdgcn_rcpf(z + 1.f);
  return __builtin_fmaf(-x, r, x);
}
__device__ inline f32x4 mfma16(short8 a, short8 b, f32x4 c){
  return __builtin_amdgcn_mfma_f32_16x16x32_bf16(
      __builtin_bit_cast(bf16x8, a), __builtin_bit_cast(bf16x8, b), c, 0, 0, 0);
}

// ---------------- Kernel A: repack weights to bf16 MFMA fragment order ------
// Frag (A or B) for 16x16x32: lane l holds M/N-index (l&15), k = (l>>4)*8+j.
// w1p used as GEMM1 A-frag (M=i,K=h); w2p used as GEMM2 B-frag (N=h,K=i).
__global__ __launch_bounds__(256) void k_prep(const float* __restrict__ w1,
                                              const float* __restrict__ w2,
                                              unsigned short* __restrict__ w1p,
                                              unsigned short* __restrict__ w2p){
  int idx = blockIdx.x * 256 + threadIdx.x;   // 0 .. 524287
  {
    // w1: [E][I][H]; packed [e][it][kt][lane][j]: w1[e][it*16+(l&15)][kt*32+(l>>4)*8+j]
    float v = w1[idx];
    int e = idx >> 16, r = idx & 65535;
    int i = r >> 7, h = r & 127;
    int it = i >> 4, il = i & 15;
    int kt = h >> 5, lh = (h >> 3) & 3, j = h & 7;
    int l = lh * 16 + il;
    size_t p = ((((size_t)e * 32 + it) * 4 + kt) * 64 + l) * 8 + j;
    w1p[p] = f2bf(v);
  }
  {
    // w2: [E][H][I]; packed [e][ht][kt][lane][j]: w2[e][ht*16+(l&15)][kt*32+(l>>4)*8+j]
    float v = w2[idx];
    int e = idx >> 16, r = idx & 65535;
    int h = r >> 9, i = r & 511;
    int ht = h >> 4, hl = h & 15;
    int kt = i >> 5, lh = (i >> 3) & 3, j = i & 7;
    int l = lh * 16 + hl;
    size_t p = ((((size_t)e * 8 + ht) * 16 + kt) * 64 + l) * 8 + j;
    w2p[p] = f2bf(v);
  }
}

// ---------------- Kernel B: gating softmax/top2 + token layernorm -----------
// Hierarchical atomics: LDS counters -> 1 global atomicAdd per (block,expert).
__global__ __launch_bounds__(256) void k_gate(const float* __restrict__ x,
                                              const float* __restrict__ gw,
                                              const float* __restrict__ gb,
                                              unsigned short* __restrict__ xn,
                                              int* __restrict__ cnt,
                                              int* __restrict__ list,
                                              float* __restrict__ score){
  __shared__ float gws[E * H];
  __shared__ float gbs[E];
  __shared__ int   lcnt[E];
  __shared__ int   gbase[E];
  __shared__ int   te[2][GATE_TPB];
  __shared__ float tsc[2][GATE_TPB];
  __shared__ int   tlp[2][GATE_TPB];

  int tid = threadIdx.x;
  for (int i = tid; i < E * H; i += 256) gws[i] = gw[i];
  if (tid < E){ gbs[tid] = gb[tid]; lcnt[tid] = 0; }
  __syncthreads();

  int wave = tid >> 6, lane = tid & 63;
  int tok0 = blockIdx.x * GATE_TPB;

  for (int t = 0; t < GATE_TPB / 4; ++t){
    int lt = wave * (GATE_TPB / 4) + t;
    int tok = tok0 + lt;
    const float* xp = x + (size_t)tok * H;
    float2 v = *(const float2*)(xp + lane * 2);

    float s = v.x + v.y;
    float sq = v.x * v.x + v.y * v.y;
    float lg[E];
    #pragma unroll
    for (int e = 0; e < E; e++)
      lg[e] = v.x * gws[e * H + lane * 2] + v.y * gws[e * H + lane * 2 + 1];

    #pragma unroll
    for (int m = 1; m < 64; m <<= 1){
      s  += __shfl_xor(s, m);
      sq += __shfl_xor(sq, m);
      #pragma unroll
      for (int e = 0; e < E; e++) lg[e] += __shfl_xor(lg[e], m);
    }

    float mu = s * (1.f / H);
    float var = sq * (1.f / H) - mu * mu;
    float rsig = rsqrtf(fmaxf(var, 0.f) + EPS);

    unsigned short b0 = f2bf((v.x - mu) * rsig);
    unsigned short b1 = f2bf((v.y - mu) * rsig);
    unsigned int packed = ((unsigned int)b1 << 16) | b0;
    *(unsigned int*)(xn + (size_t)tok * H + lane * 2) = packed;

    if (lane == 0){
      float mx = -1e30f;
      #pragma unroll
      for (int e = 0; e < E; e++){ lg[e] += gbs[e]; mx = fmaxf(mx, lg[e]); }
      float p[E], sum = 0.f;
      #pragma unroll
      for (int e = 0; e < E; e++){ p[e] = __expf(lg[e] - mx); sum += p[e]; }
      float inv = 1.f / sum;
      int e0 = 0; float p0 = p[0];
      #pragma unroll
      for (int e = 1; e < E; e++) if (p[e] > p0){ e0 = e; p0 = p[e]; }
      int e1 = -1; float p1 = -1.f;
      #pragma unroll
      for (int e = 0; e < E; e++) if (e != e0 && p[e] > p1){ e1 = e; p1 = p[e]; }
      te[0][lt] = e0; tsc[0][lt] = p0 * inv; tlp[0][lt] = atomicAdd(&lcnt[e0], 1);
      te[1][lt] = e1; tsc[1][lt] = p1 * inv; tlp[1][lt] = atomicAdd(&lcnt[e1], 1);
    }
  }
  __syncthreads();
  if (tid < E) gbase[tid] = atomicAdd(&cnt[tid], lcnt[tid]);
  __syncthreads();
  if (tid < GATE_TPB){
    int tok = tok0 + tid;
    #pragma unroll
    for (int k2 = 0; k2 < 2; k2++){
      int ee = te[k2][tid];
      int pos = gbase[ee] + tlp[k2][tid];
      list[ee * N_TOK + pos] = tok;
      score[ee * N_TOK + pos] = tsc[k2][tid];
    }
  }
}

// ---------------- Kernel C: grouped expert MLP (MFMA) -----------------------
// GEMM1 computed TRANSPOSED: t^T[i][m] = sum_h w1[i][h] * a1[m][h].
// C^T layout: lane holds token col (l&15), 4 consecutive i rows (l4*4+r).
// -> LN2 reduce = in-lane sum + 2 shuffles; a2 write = packed ds_write_b64.
__global__ __launch_bounds__(256) void k_expert(
    const unsigned short* __restrict__ xn,
    const float* __restrict__ ln1g, const float* __restrict__ ln1b,
    const unsigned short* __restrict__ w1p,
    const float* __restrict__ ln2g, const float* __restrict__ ln2b,
    const unsigned short* __restrict__ w2p,
    const float* __restrict__ b2,
    const int* __restrict__ cnt, const int* __restrict__ list,
    const float* __restrict__ score,
    float* __restrict__ out){
  int e = blockIdx.y;
  int ne = cnt[e];
  int base = blockIdx.x * TM;
  if (base >= ne) return;
  int rows = min(TM, ne - base);

  __shared__ __align__(16) unsigned short a1[TM * H];     // 8 KB, swizzled
  __shared__ __align__(16) unsigned short a2[TM * I_DIM]; // 32 KB, swizzled
  __shared__ float g1s[H], b1s[H];
  __shared__ float psum[2][TM][4];                        // [S/Q][token][wave]
  __shared__ int   toks[TM];
  __shared__ float scs[TM];

  int tid = threadIdx.x, wave = tid >> 6, lane = tid & 63;
  const int l15 = lane & 15, l4 = lane >> 4;

  if (tid < H){ g1s[tid] = ln1g[e * H + tid]; b1s[tid] = ln1b[e * H + tid]; }
  if (tid < TM){
    int gpos = base + tid;
    if (gpos < ne){ toks[tid] = list[e * N_TOK + gpos]; scs[tid] = score[e * N_TOK + gpos]; }
    else          { toks[tid] = -1;                     scs[tid] = 0.f; }
  }
  __syncthreads();

  // ---- stage a1 = gelu(xn * g1 + b1), bf16, XOR-swizzled -------------------
  {
    int r = tid >> 3, c0 = (tid & 7) * 16;
    int t_ = toks[r];
    short8 o0, o1;
    if (t_ >= 0){
      const unsigned short* xr = xn + (size_t)t_ * H + c0;
      short8 v0 = *(const short8*)xr;
      short8 v1 = *(const short8*)(xr + 8);
      #pragma unroll
      for (int j = 0; j < 8; j++){
        int c = c0 + j;
        float f = bf2f((unsigned short)v0[j]);
        o0[j] = (short)f2bf(gelu_fast(f * g1s[c] + b1s[c]));
      }
      #pragma unroll
      for (int j = 0; j < 8; j++){
        int c = c0 + 8 + j;
        float f = bf2f((unsigned short)v1[j]);
        o1[j] = (short)f2bf(gelu_fast(f * g1s[c] + b1s[c]));
      }
    } else {
      #pragma unroll
      for (int j = 0; j < 8; j++){ o0[j] = 0; o1[j] = 0; }
    }
    int byt = r * 256 + c0 * 2;
    int swz = (r & 7) << 4;
    *(short8*)((char*)a1 + (byt ^ swz)) = o0;
    *(short8*)((char*)a1 + ((byt + 16) ^ swz)) = o1;
  }
  __syncthreads();

  // ---- GEMM1^T: acc[nt][it] = C^T tile (i rows, token cols) ----------------
  // wave owns i in [wave*128, wave*128+128): it = 0..7; nt = token halves.
  f32x4 acc[2][8];
  #pragma unroll
  for (int nt = 0; nt < 2; nt++)
    #pragma unroll
    for (int it = 0; it < 8; it++){ f32x4 z = {0.f,0.f,0.f,0.f}; acc[nt][it] = z; }

  #pragma unroll
  for (int kt = 0; kt < 4; ++kt){
    short8 bfr[2];   // a1 B-frags: token col = nt*16+l15, k = kt*32 + l4*8
    #pragma unroll
    for (int nt = 0; nt < 2; nt++){
      int row = nt * 16 + l15;
      int byt = row * 256 + (kt * 32 + l4 * 8) * 2;
      bfr[nt] = *(const short8*)((const char*)a1 + (byt ^ ((row & 7) << 4)));
    }
    #pragma unroll
    for (int it = 0; it < 8; ++it){
      const short8 afr = *(const short8*)(w1p +
          ((((size_t)e * 32 + wave * 8 + it) * 4 + kt) * 64 + lane) * 8);
      acc[0][it] = mfma16(afr, bfr[0], acc[0][it]);
      acc[1][it] = mfma16(afr, bfr[1], acc[1][it]);
    }
  }

  // ---- LN2 partials: token is lane-local; reduce i over l4 groups ----------
  #pragma unroll
  for (int nt = 0; nt < 2; nt++){
    float s_ = 0.f, q_ = 0.f;
    #pragma unroll
    for (int it = 0; it < 8; it++)
      #pragma unroll
      for (int r = 0; r < 4; r++){ float v = acc[nt][it][r]; s_ += v; q_ += v * v; }
    s_ += __shfl_xor(s_, 16);  q_ += __shfl_xor(q_, 16);
    s_ += __shfl_xor(s_, 32);  q_ += __shfl_xor(q_, 32);
    if (l4 == 0){
      psum[0][nt * 16 + l15][wave] = s_;
      psum[1][nt * 16 + l15][wave] = q_;
    }
  }
  __syncthreads();

  // ---- LN2 + gelu -> a2 (bf16, packed b64 writes, swizzled) ----------------
  float rss[2], mrs[2];
  #pragma unroll
  for (int nt = 0; nt < 2; nt++){
    int token = nt * 16 + l15;
    f32x4 S4 = *(const f32x4*)&psum[0][token][0];
    f32x4 Q4 = *(const f32x4*)&psum[1][token][0];
    float S = S4[0] + S4[1] + S4[2] + S4[3];
    float Q = Q4[0] + Q4[1] + Q4[2] + Q4[3];
    float mu = S * (1.f / I_DIM);
    float var = Q * (1.f / I_DIM) - mu * mu;
    float rsig = rsqrtf(fmaxf(var, 0.f) + EPS);
    rss[nt] = rsig; mrs[nt] = mu * rsig;
  }
  #pragma unroll
  for (int it = 0; it < 8; it++){
    int i0 = wave * 128 + it * 16 + l4 * 4;
    f32x4 g2v = *(const f32x4*)(ln2g + e * I_DIM + i0);
    f32x4 b2v = *(const f32x4*)(ln2b + e * I_DIM + i0);
    #pragma unroll
    for (int nt = 0; nt < 2; nt++){
      int token = nt * 16 + l15;
      unsigned short u[4];
      #pragma unroll
      for (int r = 0; r < 4; r++){
        float t1 = __builtin_fmaf(acc[nt][it][r], rss[nt], -mrs[nt]);
        float h2 = __builtin_fmaf(t1, g2v[r], b2v[r]);
        u[r] = f2bf(gelu_fast(h2));
      }
      u32x2 w;
      w[0] = (unsigned int)u[0] | ((unsigned int)u[1] << 16);
      w[1] = (unsigned int)u[2] | ((unsigned int)u[3] << 16);
      int byt = token * 1024 + i0 * 2;
      *(u32x2*)((char*)a2 + (byt ^ ((token & 7) << 4))) = w;
    }
  }
  __syncthreads();

  // ---- GEMM2: o[32 x 128] ; wave owns h-cols [wave*32, wave*32+32) ---------
  f32x4 c2[2][2];
  #pragma unroll
  for (int mt = 0; mt < 2; mt++)
    #pragma unroll
    for (int ht = 0; ht < 2; ht++){ f32x4 z = {0.f,0.f,0.f,0.f}; c2[mt][ht] = z; }

  #pragma unroll
  for (int kt = 0; kt < 16; ++kt){
    short8 af[2];
    #pragma unroll
    for (int mt = 0; mt < 2; mt++){
      int r = mt * 16 + l15;
      int byt = r * 1024 + (kt * 32 + l4 * 8) * 2;
      af[mt] = *(const short8*)((const char*)a2 + (byt ^ ((r & 7) << 4)));
    }
    #pragma unroll
    for (int ht = 0; ht < 2; ++ht){
      const short8 bf = *(const short8*)(w2p +
          ((((size_t)e * 8 + wave * 2 + ht) * 16 + kt) * 64 + lane) * 8);
      c2[0][ht] = mfma16(af[0], bf, c2[0][ht]);
      c2[1][ht] = mfma16(af[1], bf, c2[1][ht]);
    }
  }

  // ---- epilogue: + b2, * score, atomicAdd into out -------------------------
  float bb[2];
  #pragma unroll
  for (int ht = 0; ht < 2; ht++) bb[ht] = b2[e * H + wave * 32 + ht * 16 + l15];
  #pragma unroll
  for (int mt = 0; mt < 2; mt++){
    #pragma unroll
    for (int ht = 0; ht < 2; ht++){
      #pragma unroll
      for (int r = 0; r < 4; r++){
        int row = mt * 16 + l4 * 4 + r;
        if (row < rows){
          int t_ = toks[row]; float sc = scs[row];
          int col = wave * 32 + ht * 16 + l15;
          atomicAdd(out + (size_t)t_ * H + col, (c2[mt][ht][r] + bb[ht]) * sc);
        }
      }
    }
  }
}

extern "C" void kernel_launch(void* const* d_in, const int* in_sizes, int n_in,
                              void* d_out, int out_size, void* d_ws, size_t ws_size,
                              hipStream_t stream){
  const float* x     = (const float*)d_in[0];
  const float* gw    = (const float*)d_in[1];
  const float* gb    = (const float*)d_in[2];
  const float* ln1g  = (const float*)d_in[3];
  const float* ln1b  = (const float*)d_in[4];
  const float* w1    = (const float*)d_in[5];
  const float* ln2g  = (const float*)d_in[6];
  const float* ln2b  = (const float*)d_in[7];
  const float* w2    = (const float*)d_in[8];
  const float* b2    = (const float*)d_in[9];
  float* out = (float*)d_out;

  char* w = (char*)d_ws;
  unsigned short* xn  = (unsigned short*)w;            w += (size_t)N_TOK * H * 2;
  unsigned short* w1p = (unsigned short*)w;            w += (size_t)E * I_DIM * H * 2;
  unsigned short* w2p = (unsigned short*)w;            w += (size_t)E * H * I_DIM * 2;
  int*   list  = (int*)w;                              w += (size_t)E * N_TOK * 4;
  float* score = (float*)w;                            w += (size_t)E * N_TOK * 4;
  int*   cnt   = (int*)w;                              w += 256;

  hipMemsetAsync(cnt, 0, 256, stream);
  hipMemsetAsync(out, 0, (size_t)out_size * sizeof(float), stream);

  k_prep<<<dim3((E * I_DIM * H) / 256), dim3(256), 0, stream>>>(w1, w2, w1p, w2p);
  k_gate<<<dim3(N_TOK / GATE_TPB), dim3(256), 0, stream>>>(x, gw, gb, xn, cnt, list, score);
  k_expert<<<dim3(N_TOK / TM, E), dim3(256), 0, stream>>>(
      xn, ln1g, ln1b, w1p, ln2g, ln2b, w2p, b2, cnt, list, score, out);
}